// Round 1
// baseline (195.070 us; speedup 1.0000x reference)
//
#include <hip/hip_runtime.h>
#include <hip/hip_bf16.h>

#define DD 256
#define HH 8
#define DHD 32
#define BB 32
#define NN 48

// ---------------- Kernel 0: fold Wc = Wm @ Wo, bc = Wm @ bo ----------------
__global__ __launch_bounds__(256) void fold_kernel(
    const float* __restrict__ Wm, const float* __restrict__ Wo,
    const float* __restrict__ bo, float* __restrict__ Wc, float* __restrict__ bc)
{
    int r = blockIdx.x;          // row of Wm / Wc
    int c = threadIdx.x;         // 0..255
    __shared__ float wr[DD];
    wr[c] = Wm[r * DD + c];
    __syncthreads();
    float acc = 0.f;
    for (int i = 0; i < DD; ++i) acc += wr[i] * Wo[i * DD + c];  // coalesced over c
    Wc[r * DD + c] = acc;
    if (c == 0) {
        float a = 0.f;
        for (int i = 0; i < DD; ++i) a += wr[i] * bo[i];
        bc[r] = a;
    }
}

// ---------------- Kernel 1: Q,K,V projections ----------------
__global__ __launch_bounds__(256) void qkv_kernel(
    const float* __restrict__ x,
    const float* __restrict__ Wq, const float* __restrict__ bq,
    const float* __restrict__ Wk, const float* __restrict__ bk,
    const float* __restrict__ Wv, const float* __restrict__ bv,
    float* __restrict__ Q, float* __restrict__ Kd, float* __restrict__ V)
{
    const int ROWS = 8;
    __shared__ float xs[ROWS][DD];
    int row0 = blockIdx.x * ROWS;
    int t = threadIdx.x;
    #pragma unroll
    for (int r = 0; r < ROWS; ++r) xs[r][t] = x[(row0 + r) * DD + t];
    __syncthreads();

    const float* Ws[3] = {Wq, Wk, Wv};
    const float* bs[3] = {bq, bk, bv};
    float*       Os[3] = {Q, Kd, V};
    for (int m = 0; m < 3; ++m) {
        float acc[ROWS];
        #pragma unroll
        for (int r = 0; r < ROWS; ++r) acc[r] = 0.f;
        const float4* W4 = (const float4*)(Ws[m] + t * DD);
        for (int i = 0; i < DD / 4; ++i) {
            float4 w = W4[i];
            #pragma unroll
            for (int r = 0; r < ROWS; ++r) {
                acc[r] += xs[r][4*i+0] * w.x + xs[r][4*i+1] * w.y
                        + xs[r][4*i+2] * w.z + xs[r][4*i+3] * w.w;
            }
        }
        float bias = bs[m][t];
        #pragma unroll
        for (int r = 0; r < ROWS; ++r) Os[m][(row0 + r) * DD + t] = acc[r] + bias;
    }
}

// ---------------- Kernel 2: E = exp(scores - rowmax) ----------------
__global__ __launch_bounds__(256) void scores_kernel(
    const float* __restrict__ Q, const float* __restrict__ K, float* __restrict__ E)
{
    int bh = blockIdx.x;               // b*H + h
    int b = bh / HH, h = bh % HH;
    __shared__ float qs[NN][DHD];
    __shared__ float ks[NN][DHD];
    __shared__ float sc[NN][NN + 1];
    __shared__ float rowmax[NN];
    int tid = threadIdx.x;

    for (int e = tid; e < NN * DHD; e += 256) {
        int n = e / DHD, j = e % DHD;
        qs[n][j] = Q[(b * NN + n) * DD + h * DHD + j];
        ks[n][j] = K[(b * NN + n) * DD + h * DHD + j];
    }
    __syncthreads();
    const float scale = 0.17677669529663687f; // 1/sqrt(32)
    for (int e = tid; e < NN * NN; e += 256) {
        int qi = e / NN, ki = e % NN;
        float s = 0.f;
        #pragma unroll
        for (int j = 0; j < DHD; ++j) s += qs[qi][j] * ks[ki][j];
        sc[qi][ki] = s * scale;
    }
    __syncthreads();
    if (tid < NN) {
        float mx = -1e30f;
        for (int k = 0; k < NN; ++k) mx = fmaxf(mx, sc[tid][k]);
        rowmax[tid] = mx;
    }
    __syncthreads();
    for (int e = tid; e < NN * NN; e += 256) {
        int qi = e / NN, ki = e % NN;
        E[(bh * NN + qi) * NN + ki] = __expf(sc[qi][ki] - rowmax[qi]);
    }
}

// ---------------- Kernel 3: per-target aggregation -> P, cnt ----------------
__global__ __launch_bounds__(384) void aggregate_kernel(
    const float* __restrict__ E, const float* __restrict__ V,
    const int* __restrict__ adj, float* __restrict__ P, float* __restrict__ cntbuf)
{
    int bt = blockIdx.x;               // b*N + t
    int b = bt / NN, t = bt % NN;
    __shared__ float m[NN];
    __shared__ float invd[HH][NN];
    __shared__ float yv[HH][NN];
    __shared__ float cnt_s;
    int tid = threadIdx.x;             // 0..383 = (h,?) = 8*48

    if (tid < NN) m[tid] = (adj[(b * NN + tid) * NN + t] > 0) ? 1.f : 0.f;
    __syncthreads();
    if (tid == 0) {
        float c = 0.f;
        for (int s = 0; s < NN; ++s) c += m[s];
        cnt_s = c;
        cntbuf[bt] = c;
    }
    __syncthreads();
    if (cnt_s == 0.f) return;          // fallback handled in final kernel

    // Phase A: invd[h][q] = m[q] / (sum_k m[k]*E[h,q,k])
    {
        int h = tid / NN, q = tid % NN;
        const float* Erow = E + ((b * HH + h) * NN + q) * NN;
        float d = 0.f;
        for (int k = 0; k < NN; ++k) d += m[k] * Erow[k];
        invd[h][q] = (m[q] > 0.f) ? (1.f / d) : 0.f;
    }
    __syncthreads();
    // Phase B: yv[h][k] = m[k] * sum_q E[h,q,k] * invd[h][q]
    {
        int h = tid / NN, k = tid % NN;
        const float* Eh = E + (b * HH + h) * NN * NN;
        float acc = 0.f;
        for (int q = 0; q < NN; ++q) acc += Eh[q * NN + k] * invd[h][q];
        yv[h][k] = m[k] * acc;
    }
    __syncthreads();
    // Phase C: P[bt][d] = sum_k yv[h(d)][k] * V[b,k,d]
    if (tid < DD) {
        int h = tid / DHD;
        float p = 0.f;
        for (int k = 0; k < NN; ++k) p += yv[h][k] * V[(b * NN + k) * DD + tid];
        P[bt * DD + tid] = p;
    }
}

// ---------------- Kernel 4: final map + fallback + write ----------------
__global__ __launch_bounds__(256) void final_kernel(
    const float* __restrict__ P, const float* __restrict__ cnt,
    const float* __restrict__ Wc, const float* __restrict__ bc,
    const float* __restrict__ bm, const float* __restrict__ fallback,
    float* __restrict__ out, int out_off)
{
    const int ROWS = 8;
    __shared__ float ps[ROWS][DD];
    __shared__ float cs[ROWS];
    int row0 = blockIdx.x * ROWS;
    int t = threadIdx.x;
    #pragma unroll
    for (int r = 0; r < ROWS; ++r) ps[r][t] = P[(row0 + r) * DD + t];
    if (t < ROWS) cs[t] = cnt[row0 + t];
    __syncthreads();

    float acc[ROWS];
    #pragma unroll
    for (int r = 0; r < ROWS; ++r) acc[r] = 0.f;
    const float4* W4 = (const float4*)(Wc + t * DD);
    for (int i = 0; i < DD / 4; ++i) {
        float4 w = W4[i];
        #pragma unroll
        for (int r = 0; r < ROWS; ++r) {
            acc[r] += ps[r][4*i+0] * w.x + ps[r][4*i+1] * w.y
                    + ps[r][4*i+2] * w.z + ps[r][4*i+3] * w.w;
        }
    }
    float bcv = bc[t], bmv = bm[t];
    #pragma unroll
    for (int r = 0; r < ROWS; ++r) {
        int row = row0 + r;
        float c = cs[r];
        float o;
        if (c > 0.f) o = acc[r] / (c * c) + bcv / c + bmv;
        else         o = fallback[row * DD + t];
        out[row * 1024 + out_off + t] = o;
    }
}

// ---------------- Kernel 5: passthrough copies ----------------
__global__ __launch_bounds__(256) void copy_kernel(
    const float4* __restrict__ af, const float4* __restrict__ sf, float4* __restrict__ out)
{
    int idx = blockIdx.x * 256 + threadIdx.x;   // B*N*D/4 = 98304, grid = 384
    int row = idx >> 6, c = idx & 63;
    out[row * 256 + 128 + c] = af[idx];
    out[row * 256 + 192 + c] = sf[idx];
}

extern "C" void kernel_launch(void* const* d_in, const int* in_sizes, int n_in,
                              void* d_out, int out_size, void* d_ws, size_t ws_size,
                              hipStream_t stream)
{
    const float* async_fea = (const float*)d_in[0];
    const float* sync_fea  = (const float*)d_in[1];
    const int*   async_adj = (const int*)d_in[2];
    const int*   sync_adj  = (const int*)d_in[3];

    float* out = (float*)d_out;
    float* ws  = (float*)d_ws;

    // scratch layout (floats), reused across the two aggregates (stream-ordered)
    float* Q   = ws;                 // 393216
    float* Kb  = ws + 393216;        // 393216
    float* Vb  = ws + 786432;        // 393216
    float* E   = ws + 1179648;       // 589824
    float* P   = ws + 1769472;       // 393216
    float* cnt = ws + 2162688;       // 1536
    float* Wc  = ws + 2164224;       // 65536
    float* bc  = ws + 2229760;       // 256   -> total 2230016 floats (~8.9 MB)

    for (int agg = 0; agg < 2; ++agg) {
        const float* x_src;
        const int*   adj;
        const float* fb;
        int wbase, out_off;
        if (agg == 0) { // refined_async: src=sync, adj=sync, fallback=async, a_ weights
            x_src = sync_fea;  adj = sync_adj;  fb = async_fea;  wbase = 4;  out_off = 0;
        } else {        // refined_sync: src=async, adj=async, fallback=sync, s_ weights
            x_src = async_fea; adj = async_adj; fb = sync_fea;   wbase = 14; out_off = 256;
        }
        const float* Wq = (const float*)d_in[wbase + 0];
        const float* bq = (const float*)d_in[wbase + 1];
        const float* Wk = (const float*)d_in[wbase + 2];
        const float* bk = (const float*)d_in[wbase + 3];
        const float* Wv = (const float*)d_in[wbase + 4];
        const float* bv = (const float*)d_in[wbase + 5];
        const float* Wo = (const float*)d_in[wbase + 6];
        const float* bo = (const float*)d_in[wbase + 7];
        const float* Wm = (const float*)d_in[wbase + 8];
        const float* bm = (const float*)d_in[wbase + 9];

        fold_kernel<<<DD, 256, 0, stream>>>(Wm, Wo, bo, Wc, bc);
        qkv_kernel<<<BB * NN / 8, 256, 0, stream>>>(x_src, Wq, bq, Wk, bk, Wv, bv, Q, Kb, Vb);
        scores_kernel<<<BB * HH, 256, 0, stream>>>(Q, Kb, E);
        aggregate_kernel<<<BB * NN, 384, 0, stream>>>(E, Vb, adj, P, cnt);
        final_kernel<<<BB * NN / 8, 256, 0, stream>>>(P, cnt, Wc, bc, bm, fb, out, out_off);
    }
    copy_kernel<<<384, 256, 0, stream>>>((const float4*)async_fea,
                                         (const float4*)sync_fea, (float4*)out);
}

// Round 2
// 93.635 us; speedup vs baseline: 2.0833x; 2.0833x over previous
//
#include <hip/hip_runtime.h>

#define DD 256
#define HH 8
#define NN 48
#define BB 32

// Swizzled float-index for LDS tiles with 32-float (128 B) rows:
// float4-slot s = jj ^ (row&7). Keeps ds_read_b128 column reads <=2-way.
__device__ __forceinline__ int swz4(int row, int jj) {
    return (row << 5) + ((jj ^ (row & 7)) << 2);
}

// ---------- Launch 1: qkv tiled GEMM (blocks 0..575) + fold Wc=Wm@Wo (576..639) ----------
__global__ __launch_bounds__(256) void prep_kernel(
    const float* __restrict__ async_fea, const float* __restrict__ sync_fea,
    const float* __restrict__ aWq, const float* __restrict__ abq,
    const float* __restrict__ aWk, const float* __restrict__ abk,
    const float* __restrict__ aWv, const float* __restrict__ abv,
    const float* __restrict__ aWm, const float* __restrict__ aWo, const float* __restrict__ abo,
    const float* __restrict__ sWq, const float* __restrict__ sbq,
    const float* __restrict__ sWk, const float* __restrict__ sbk,
    const float* __restrict__ sWv, const float* __restrict__ sbv,
    const float* __restrict__ sWm, const float* __restrict__ sWo, const float* __restrict__ sbo,
    float* __restrict__ QKV0, float* __restrict__ QKV1,
    float* __restrict__ Wc0, float* __restrict__ Wc1,
    float* __restrict__ bc0, float* __restrict__ bc1)
{
    __shared__ float smem[4096];
    int bid = blockIdx.x, tid = threadIdx.x;
    if (bid < 576) {
        // tiled GEMM: 64 rows x 64 outs, K=256 in 8 chunks of 32
        int agg = bid / 288, rem = bid % 288;
        int rt = rem / 12, ot = rem % 12;
        int mat = ot >> 2, ob = (ot & 3) << 6;
        const float* x = agg ? async_fea : sync_fea;
        const float* W;
        const float* bias;
        if (agg == 0) {
            W    = (mat == 0) ? aWq : (mat == 1) ? aWk : aWv;
            bias = (mat == 0) ? abq : (mat == 1) ? abk : abv;
        } else {
            W    = (mat == 0) ? sWq : (mat == 1) ? sWk : sWv;
            bias = (mat == 0) ? sbq : (mat == 1) ? sbk : sbv;
        }
        float* outQ = agg ? QKV1 : QKV0;
        float* xs = smem;          // 64x32
        float* wt = smem + 2048;   // 64x32
        int rbase = rt * 64;
        int ty = tid >> 4, tx = tid & 15;
        float acc[4][4];
        #pragma unroll
        for (int i = 0; i < 4; ++i)
            #pragma unroll
            for (int j = 0; j < 4; ++j) acc[i][j] = 0.f;
        const float4* x4g = (const float4*)x;
        const float4* w4g = (const float4*)W;
        for (int ch = 0; ch < 8; ++ch) {
            __syncthreads();
            #pragma unroll
            for (int l = 0; l < 2; ++l) {
                int e4 = l * 256 + tid;
                int rr = e4 >> 3, jj = e4 & 7;
                float4 xv = x4g[(rbase + rr) * 64 + ch * 8 + jj];
                *(float4*)&xs[swz4(rr, jj)] = xv;
                float4 wv = w4g[(ob + rr) * 64 + ch * 8 + jj];
                *(float4*)&wt[swz4(rr, jj)] = wv;
            }
            __syncthreads();
            #pragma unroll
            for (int jj = 0; jj < 8; ++jj) {
                float4 xv[4], wv[4];
                #pragma unroll
                for (int i = 0; i < 4; ++i) xv[i] = *(const float4*)&xs[swz4(ty * 4 + i, jj)];
                #pragma unroll
                for (int j = 0; j < 4; ++j) wv[j] = *(const float4*)&wt[swz4(j * 16 + tx, jj)];
                #pragma unroll
                for (int i = 0; i < 4; ++i)
                    #pragma unroll
                    for (int j = 0; j < 4; ++j)
                        acc[i][j] += xv[i].x * wv[j].x + xv[i].y * wv[j].y
                                   + xv[i].z * wv[j].z + xv[i].w * wv[j].w;
            }
        }
        #pragma unroll
        for (int j = 0; j < 4; ++j) {
            float bv = bias[ob + j * 16 + tx];
            #pragma unroll
            for (int i = 0; i < 4; ++i) {
                int row = rbase + ty * 4 + i;
                outQ[row * 768 + ot * 64 + j * 16 + tx] = acc[i][j] + bv;
            }
        }
    } else {
        // fold: Wc = Wm @ Wo, bc = Wm @ bo ; 8 rows per block
        int fid = bid - 576;
        int agg = fid / 32, rb = (fid % 32) * 8;
        const float* Wm = agg ? sWm : aWm;
        const float* Wo = agg ? sWo : aWo;
        const float* bo = agg ? sbo : abo;
        float* Wc = agg ? Wc1 : Wc0;
        float* bc = agg ? bc1 : bc0;
        float* wm  = smem;          // 8x256
        float* bos = smem + 2048;   // 256
        #pragma unroll
        for (int l = 0; l < 8; ++l) {
            int e = l * 256 + tid;
            wm[e] = Wm[rb * 256 + e];
        }
        bos[tid] = bo[tid];
        __syncthreads();
        float acc[8];
        #pragma unroll
        for (int r = 0; r < 8; ++r) acc[r] = 0.f;
        for (int i = 0; i < 256; ++i) {
            float woc = Wo[i * 256 + tid];
            #pragma unroll
            for (int r = 0; r < 8; ++r) acc[r] += wm[r * 256 + i] * woc;
        }
        #pragma unroll
        for (int r = 0; r < 8; ++r) Wc[(rb + r) * 256 + tid] = acc[r];
        if (tid < 8) {
            float s = 0.f;
            for (int i = 0; i < 256; ++i) s += wm[tid * 256 + i] * bos[i];
            bc[rb + tid] = s;
        }
    }
}

// ---------- Launch 2: E = exp(scores - rowmax), per (agg, b, h) ----------
__global__ __launch_bounds__(256) void scores_kernel(
    const float* __restrict__ QKV0, const float* __restrict__ QKV1,
    float* __restrict__ E0, float* __restrict__ E1)
{
    __shared__ float qs[1536], ks[1536], sc[48 * 49], rmax[48];
    int sid = blockIdx.x, tid = threadIdx.x;
    int agg = sid >> 8, bh = sid & 255;
    int b = bh >> 3, h = bh & 7;
    const float4* Q4 = (const float4*)(agg ? QKV1 : QKV0);
    float* E = agg ? E1 : E0;
    for (int e4 = tid; e4 < 384; e4 += 256) {
        int n = e4 >> 3, jj = e4 & 7;
        int base = (b * 48 + n) * 192 + h * 8 + jj;
        *(float4*)&qs[swz4(n, jj)] = Q4[base];
        *(float4*)&ks[swz4(n, jj)] = Q4[base + 64];   // K is +256 floats
    }
    __syncthreads();
    const float scale = 0.17677669529663687f;  // 1/sqrt(32)
    for (int e = tid; e < 2304; e += 256) {
        int qi = e / 48, ki = e % 48;
        float s = 0.f;
        #pragma unroll
        for (int jj = 0; jj < 8; ++jj) {
            float4 a = *(const float4*)&qs[swz4(qi, jj)];
            float4 c = *(const float4*)&ks[swz4(ki, jj)];
            s += a.x * c.x + a.y * c.y + a.z * c.z + a.w * c.w;
        }
        sc[qi * 49 + ki] = s * scale;
    }
    __syncthreads();
    if (tid < 48) {
        float mx = -1e30f;
        for (int k = 0; k < 48; ++k) mx = fmaxf(mx, sc[tid * 49 + k]);
        rmax[tid] = mx;
    }
    __syncthreads();
    float* Eb = E + (b * 8 + h) * 2304;
    for (int e = tid; e < 2304; e += 256) {
        int qi = e / 48, ki = e % 48;
        Eb[qi * 48 + ki] = __expf(sc[qi * 49 + ki] - rmax[qi]);
    }
}

// ---------- Launch 3: per-(agg,b,8-target-group) aggregation -> P, cnt ----------
__global__ __launch_bounds__(384) void aggregate_kernel(
    const float* __restrict__ E0, const float* __restrict__ E1,
    const float* __restrict__ QKV0, const float* __restrict__ QKV1,
    const int* __restrict__ sync_adj, const int* __restrict__ async_adj,
    float* __restrict__ P0, float* __restrict__ P1,
    float* __restrict__ cnt0, float* __restrict__ cnt1)
{
    __shared__ float Vs[48 * 256];      // 48 KB
    __shared__ float msk[8][48];
    __shared__ float invd[8][384];      // [tt][h*48+q]
    __shared__ float yv[8][384];        // [tt][h*48+k]
    int bid = blockIdx.x, tid = threadIdx.x;
    int agg = bid / 192, rem = bid % 192;
    int b = rem / 6, tg = rem % 6;
    const float* E = (agg ? E1 : E0) + b * 18432;
    const float* V = (agg ? QKV1 : QKV0) + b * 48 * 768 + 512;
    const int* adj = agg ? async_adj : sync_adj;
    float* P   = agg ? P1 : P0;
    float* cnt = agg ? cnt1 : cnt0;

    // stage V [48][256] (row stride 768 in global)
    const float4* V4g = (const float4*)V;
    float4* Vs4w = (float4*)Vs;
    for (int e4 = tid; e4 < 3072; e4 += 384) {
        int k = e4 >> 6, d4 = e4 & 63;
        Vs4w[k * 64 + d4] = V4g[k * 192 + d4];
    }
    // masks for the 8 targets
    {
        int tt = tid / 48, s = tid % 48;
        msk[tt][s] = (adj[(b * 48 + s) * 48 + tg * 8 + tt] > 0) ? 1.f : 0.f;
    }
    __syncthreads();
    if (tid < 8) {
        float c = 0.f;
        for (int s = 0; s < 48; ++s) c += msk[tid][s];
        cnt[b * 48 + tg * 8 + tid] = c;
    }
    // Phase A: invd[tt][h,q] = m[q]/ (sum_k m[k] E[h,q,k])
    {
        int h = tid / 48, q = tid % 48;
        float4 ev[12];
        const float4* Er4 = (const float4*)(E + (h * 48 + q) * 48);
        #pragma unroll
        for (int kk = 0; kk < 12; ++kk) ev[kk] = Er4[kk];
        #pragma unroll
        for (int tt = 0; tt < 8; ++tt) {
            const float* mr = msk[tt];
            float s = 0.f;
            #pragma unroll
            for (int kk = 0; kk < 12; ++kk) {
                float4 m4 = *(const float4*)&mr[kk * 4];
                s += ev[kk].x * m4.x + ev[kk].y * m4.y + ev[kk].z * m4.z + ev[kk].w * m4.w;
            }
            invd[tt][tid] = (mr[q] > 0.f) ? (1.f / s) : 0.f;
        }
    }
    __syncthreads();
    // Phase B: yv[tt][h,k] = m[k] * sum_q E[h,q,k] * invd[tt][h,q]
    {
        int h = tid / 48, k = tid % 48;
        float accb[8];
        #pragma unroll
        for (int tt = 0; tt < 8; ++tt) accb[tt] = 0.f;
        const float* Eh = E + h * 2304 + k;
        for (int q4 = 0; q4 < 12; ++q4) {
            float e0 = Eh[(q4 * 4 + 0) * 48];
            float e1 = Eh[(q4 * 4 + 1) * 48];
            float e2 = Eh[(q4 * 4 + 2) * 48];
            float e3 = Eh[(q4 * 4 + 3) * 48];
            #pragma unroll
            for (int tt = 0; tt < 8; ++tt) {
                float4 iv = *(const float4*)&invd[tt][h * 48 + q4 * 4];
                accb[tt] += e0 * iv.x + e1 * iv.y + e2 * iv.z + e3 * iv.w;
            }
        }
        #pragma unroll
        for (int tt = 0; tt < 8; ++tt) yv[tt][tid] = msk[tt][k] * accb[tt];
    }
    __syncthreads();
    // Phase C: P[tt][d] = sum_k yv[tt][h(d)][k] * Vs[k][d]
    {
        const float4* Vs4 = (const float4*)Vs;
        float4* P4o = (float4*)(P + (b * 48 + tg * 8) * 256);
        for (int e4 = tid; e4 < 512; e4 += 384) {
            int tt = e4 >> 6, d4 = e4 & 63;
            const float* yr = &yv[tt][(d4 >> 3) * 48];
            float4 p = {0.f, 0.f, 0.f, 0.f};
            for (int k = 0; k < 48; ++k) {
                float yval = yr[k];
                float4 vv = Vs4[k * 64 + d4];
                p.x += yval * vv.x; p.y += yval * vv.y;
                p.z += yval * vv.z; p.w += yval * vv.w;
            }
            P4o[tt * 64 + d4] = p;
        }
    }
}

// ---------- Launch 4: final map (P @ Wc^T) + fallback + passthrough copy ----------
__global__ __launch_bounds__(256) void final_kernel(
    const float* __restrict__ P0, const float* __restrict__ P1,
    const float* __restrict__ cnt0, const float* __restrict__ cnt1,
    const float* __restrict__ Wc0, const float* __restrict__ Wc1,
    const float* __restrict__ bc0, const float* __restrict__ bc1,
    const float* __restrict__ abm, const float* __restrict__ sbm,
    const float* __restrict__ async_fea, const float* __restrict__ sync_fea,
    float* __restrict__ out)
{
    __shared__ float xs[1024], wt[2048];
    int bid = blockIdx.x, tid = threadIdx.x;
    int agg = bid / 192, rem = bid % 192;
    int rt = rem >> 2, ot = rem & 3;
    int rbase = rt * 32, ob = ot * 64;
    const float* P   = agg ? P1 : P0;
    const float* cnt = agg ? cnt1 : cnt0;
    const float* Wc  = agg ? Wc1 : Wc0;
    const float* bc  = agg ? bc1 : bc0;
    const float* bm  = agg ? sbm : abm;
    const float* fb  = agg ? sync_fea : async_fea;  // fallback == passthrough source

    // passthrough copy: rows rbase..+31, 64 cols -> out cols 512 + agg*256 + ot*64
    const float4* fb4 = (const float4*)fb;
    float4* out4 = (float4*)out;
    #pragma unroll
    for (int l = 0; l < 2; ++l) {
        int e4 = l * 256 + tid;
        int rr = e4 >> 4, cc = e4 & 15;
        out4[(rbase + rr) * 256 + 128 + agg * 64 + ot * 16 + cc] =
            fb4[(rbase + rr) * 64 + ot * 16 + cc];
    }

    int ty = tid >> 4, tx = tid & 15;
    float acc[2][4];
    #pragma unroll
    for (int i = 0; i < 2; ++i)
        #pragma unroll
        for (int j = 0; j < 4; ++j) acc[i][j] = 0.f;
    const float4* P4 = (const float4*)P;
    const float4* W4 = (const float4*)Wc;
    for (int ch = 0; ch < 8; ++ch) {
        __syncthreads();
        {
            int rr = tid >> 3, jj = tid & 7;
            *(float4*)&xs[swz4(rr, jj)] = P4[(rbase + rr) * 64 + ch * 8 + jj];
        }
        #pragma unroll
        for (int l = 0; l < 2; ++l) {
            int e4 = l * 256 + tid;
            int rr = e4 >> 3, jj = e4 & 7;
            *(float4*)&wt[swz4(rr, jj)] = W4[(ob + rr) * 64 + ch * 8 + jj];
        }
        __syncthreads();
        #pragma unroll
        for (int jj = 0; jj < 8; ++jj) {
            float4 xv[2], wv[4];
            #pragma unroll
            for (int i = 0; i < 2; ++i) xv[i] = *(const float4*)&xs[swz4(ty * 2 + i, jj)];
            #pragma unroll
            for (int j = 0; j < 4; ++j) wv[j] = *(const float4*)&wt[swz4(j * 16 + tx, jj)];
            #pragma unroll
            for (int i = 0; i < 2; ++i)
                #pragma unroll
                for (int j = 0; j < 4; ++j)
                    acc[i][j] += xv[i].x * wv[j].x + xv[i].y * wv[j].y
                               + xv[i].z * wv[j].z + xv[i].w * wv[j].w;
        }
    }
    #pragma unroll
    for (int i = 0; i < 2; ++i) {
        int row = rbase + ty * 2 + i;
        float c = cnt[row];
        bool has = c > 0.f;
        float inv1 = has ? 1.f / c : 0.f;
        float inv2 = inv1 * inv1;
        #pragma unroll
        for (int j = 0; j < 4; ++j) {
            int o = ob + j * 16 + tx;
            float val = has ? acc[i][j] * inv2 + bc[o] * inv1 + bm[o]
                            : fb[row * 256 + o];
            out[row * 1024 + agg * 256 + o] = val;
        }
    }
}

extern "C" void kernel_launch(void* const* d_in, const int* in_sizes, int n_in,
                              void* d_out, int out_size, void* d_ws, size_t ws_size,
                              hipStream_t stream)
{
    const float* async_fea = (const float*)d_in[0];
    const float* sync_fea  = (const float*)d_in[1];
    const int*   async_adj = (const int*)d_in[2];
    const int*   sync_adj  = (const int*)d_in[3];
    const float* aWq = (const float*)d_in[4];
    const float* abq = (const float*)d_in[5];
    const float* aWk = (const float*)d_in[6];
    const float* abk = (const float*)d_in[7];
    const float* aWv = (const float*)d_in[8];
    const float* abv = (const float*)d_in[9];
    const float* aWo = (const float*)d_in[10];
    const float* abo = (const float*)d_in[11];
    const float* aWm = (const float*)d_in[12];
    const float* abm = (const float*)d_in[13];
    const float* sWq = (const float*)d_in[14];
    const float* sbq = (const float*)d_in[15];
    const float* sWk = (const float*)d_in[16];
    const float* sbk = (const float*)d_in[17];
    const float* sWv = (const float*)d_in[18];
    const float* sbv = (const float*)d_in[19];
    const float* sWo = (const float*)d_in[20];
    const float* sbo = (const float*)d_in[21];
    const float* sWm = (const float*)d_in[22];
    const float* sbm = (const float*)d_in[23];

    float* ws_f = (float*)d_ws;
    float* QKV0 = ws_f;                    // 1536*768
    float* QKV1 = QKV0 + 1179648;
    float* E0   = QKV1 + 1179648;          // 32*8*48*48
    float* E1   = E0 + 589824;
    float* P0   = E1 + 589824;             // 1536*256
    float* P1   = P0 + 393216;
    float* cnt0 = P1 + 393216;             // 1536
    float* cnt1 = cnt0 + 1536;
    float* Wc0  = cnt1 + 1536;             // 256*256
    float* Wc1  = Wc0 + 65536;
    float* bc0  = Wc1 + 65536;             // 256
    float* bc1  = bc0 + 256;

    prep_kernel<<<640, 256, 0, stream>>>(
        async_fea, sync_fea,
        aWq, abq, aWk, abk, aWv, abv, aWm, aWo, abo,
        sWq, sbq, sWk, sbk, sWv, sbv, sWm, sWo, sbo,
        QKV0, QKV1, Wc0, Wc1, bc0, bc1);
    scores_kernel<<<512, 256, 0, stream>>>(QKV0, QKV1, E0, E1);
    aggregate_kernel<<<384, 384, 0, stream>>>(E0, E1, QKV0, QKV1,
                                              sync_adj, async_adj, P0, P1, cnt0, cnt1);
    final_kernel<<<384, 256, 0, stream>>>(P0, P1, cnt0, cnt1, Wc0, Wc1, bc0, bc1,
                                          abm, sbm, async_fea, sync_fea, (float*)d_out);
}

// Round 3
// 91.927 us; speedup vs baseline: 2.1220x; 1.0186x over previous
//
#include <hip/hip_runtime.h>

#define DD 256
#define HH 8
#define NN 48
#define BB 32

typedef __attribute__((ext_vector_type(8))) short short8v;   // 8 bf16 (4 VGPRs)
typedef __attribute__((ext_vector_type(4))) float f32x4;

// Swizzled float-index for LDS tiles with 32-float (128 B) rows.
__device__ __forceinline__ int swz4(int row, int jj) {
    return (row << 5) + ((jj ^ (row & 7)) << 2);
}

// fp32 -> bf16 with round-to-nearest-even
__device__ __forceinline__ unsigned short f2bf(float f) {
    union { float f; unsigned u; } v; v.f = f;
    unsigned u = v.u;
    return (unsigned short)((u + 0x7FFFu + ((u >> 16) & 1u)) >> 16);
}

// ---------- Launch 0: bf16 conversion of X and W (blocks 0..575) + fold (576..639) ----------
__global__ __launch_bounds__(256) void convert_fold_kernel(
    const float* __restrict__ async_fea, const float* __restrict__ sync_fea,
    const float* __restrict__ aWq, const float* __restrict__ aWk, const float* __restrict__ aWv,
    const float* __restrict__ sWq, const float* __restrict__ sWk, const float* __restrict__ sWv,
    const float* __restrict__ aWm, const float* __restrict__ aWo, const float* __restrict__ abo,
    const float* __restrict__ sWm, const float* __restrict__ sWo, const float* __restrict__ sbo,
    unsigned short* __restrict__ Xb, unsigned short* __restrict__ Wb,
    float* __restrict__ Wc0, float* __restrict__ Wc1,
    float* __restrict__ bc0, float* __restrict__ bc1)
{
    __shared__ float smem[2304];
    int bid = blockIdx.x, tid = threadIdx.x;
    if (bid < 384) {
        // X: [agg][1536][256], agg0 <- sync_fea, agg1 <- async_fea. 786432 elems.
        int g = bid * 2048 + tid * 8;
        const float* src;
        int off;
        if (g < 393216) { src = sync_fea;  off = g; }
        else            { src = async_fea; off = g - 393216; }
        float4 x0 = *(const float4*)(src + off);
        float4 x1 = *(const float4*)(src + off + 4);
        union { unsigned short u[8]; uint4 v; } r;
        r.u[0] = f2bf(x0.x); r.u[1] = f2bf(x0.y); r.u[2] = f2bf(x0.z); r.u[3] = f2bf(x0.w);
        r.u[4] = f2bf(x1.x); r.u[5] = f2bf(x1.y); r.u[6] = f2bf(x1.z); r.u[7] = f2bf(x1.w);
        *(uint4*)(Xb + g) = r.v;
    } else if (bid < 576) {
        // W: [agg][768][256], rows 0..255=Wq, 256..511=Wk, 512..767=Wv. 393216 elems.
        int g = (bid - 384) * 2048 + tid * 8;
        int agg = g / 196608;
        int e = g - agg * 196608;
        int rr = e >> 8, c = e & 255;
        const float* Wsrc;
        if (agg == 0) Wsrc = (rr < 256) ? aWq : (rr < 512) ? aWk : aWv;
        else          Wsrc = (rr < 256) ? sWq : (rr < 512) ? sWk : sWv;
        const float* srow = Wsrc + (rr & 255) * 256 + c;
        float4 x0 = *(const float4*)(srow);
        float4 x1 = *(const float4*)(srow + 4);
        union { unsigned short u[8]; uint4 v; } r;
        r.u[0] = f2bf(x0.x); r.u[1] = f2bf(x0.y); r.u[2] = f2bf(x0.z); r.u[3] = f2bf(x0.w);
        r.u[4] = f2bf(x1.x); r.u[5] = f2bf(x1.y); r.u[6] = f2bf(x1.z); r.u[7] = f2bf(x1.w);
        *(uint4*)(Wb + g) = r.v;
    } else {
        // fold: Wc = Wm @ Wo (fp32), bc = Wm @ bo ; 8 rows per block
        int fid = bid - 576;
        int agg = fid / 32, rb = (fid % 32) * 8;
        const float* Wm = agg ? sWm : aWm;
        const float* Wo = agg ? sWo : aWo;
        const float* bo = agg ? sbo : abo;
        float* Wc = agg ? Wc1 : Wc0;
        float* bc = agg ? bc1 : bc0;
        float* wm  = smem;          // 8x256
        float* bos = smem + 2048;   // 256
        #pragma unroll
        for (int l = 0; l < 8; ++l) wm[l * 256 + tid] = Wm[rb * 256 + l * 256 + tid];
        bos[tid] = bo[tid];
        __syncthreads();
        float acc[8];
        #pragma unroll
        for (int r = 0; r < 8; ++r) acc[r] = 0.f;
        for (int i = 0; i < 256; ++i) {
            float woc = Wo[i * 256 + tid];
            #pragma unroll
            for (int r = 0; r < 8; ++r) acc[r] += wm[r * 256 + i] * woc;
        }
        #pragma unroll
        for (int r = 0; r < 8; ++r) Wc[(rb + r) * 256 + tid] = acc[r];
        if (tid < 8) {
            float s = 0.f;
            for (int i = 0; i < 256; ++i) s += wm[tid * 256 + i] * bos[i];
            bc[rb + tid] = s;
        }
    }
}

// ---------- Launch 1: QKV via MFMA bf16. Wave = 16x64 strip, direct global frag loads ----------
__global__ __launch_bounds__(256) void qkv_mfma(
    const unsigned short* __restrict__ Xb, const unsigned short* __restrict__ Wb,
    const float* __restrict__ abq, const float* __restrict__ abk, const float* __restrict__ abv,
    const float* __restrict__ sbq, const float* __restrict__ sbk, const float* __restrict__ sbv,
    float* __restrict__ QKV0, float* __restrict__ QKV1)
{
    int bid = blockIdx.x;
    int agg = bid / 288, rem = bid % 288;
    int rt = rem / 12, ct = rem % 12;           // 24 row-tiles x 12 col-tiles
    int wave = threadIdx.x >> 6, lane = threadIdx.x & 63;
    int row0 = rt * 64 + wave * 16;
    int col0 = ct * 64;
    const unsigned short* Xp = Xb + agg * 393216 + (row0 + (lane & 15)) * 256 + ((lane >> 4) << 3);
    const unsigned short* Wp = Wb + agg * 196608 + (col0 + (lane & 15)) * 256 + ((lane >> 4) << 3);
    f32x4 acc[4] = {{0,0,0,0},{0,0,0,0},{0,0,0,0},{0,0,0,0}};
    #pragma unroll
    for (int kk = 0; kk < 256; kk += 32) {
        short8v a = *(const short8v*)(Xp + kk);
        #pragma unroll
        for (int j = 0; j < 4; ++j) {
            short8v b = *(const short8v*)(Wp + j * 16 * 256 + kk);
            acc[j] = __builtin_amdgcn_mfma_f32_16x16x32_bf16(a, b, acc[j], 0, 0, 0);
        }
    }
    int mat = col0 >> 8;
    int colm = col0 & 255;
    const float* bias = agg ? (mat == 0 ? sbq : mat == 1 ? sbk : sbv)
                            : (mat == 0 ? abq : mat == 1 ? abk : abv);
    float* outQ = agg ? QKV1 : QKV0;
    #pragma unroll
    for (int j = 0; j < 4; ++j) {
        float bv = bias[colm + j * 16 + (lane & 15)];
        #pragma unroll
        for (int i = 0; i < 4; ++i) {
            int m = ((lane >> 4) << 2) + i;
            outQ[(row0 + m) * 768 + col0 + j * 16 + (lane & 15)] = acc[j][i] + bv;
        }
    }
}

// ---------- Launch 2: E = exp(scores - rowmax), per (agg, b, h) ----------
__global__ __launch_bounds__(256) void scores_kernel(
    const float* __restrict__ QKV0, const float* __restrict__ QKV1,
    float* __restrict__ E0, float* __restrict__ E1)
{
    __shared__ float qs[1536], ks[1536], sc[48 * 49], rmax[48];
    int sid = blockIdx.x, tid = threadIdx.x;
    int agg = sid >> 8, bh = sid & 255;
    int b = bh >> 3, h = bh & 7;
    const float4* Q4 = (const float4*)(agg ? QKV1 : QKV0);
    float* E = agg ? E1 : E0;
    for (int e4 = tid; e4 < 384; e4 += 256) {
        int n = e4 >> 3, jj = e4 & 7;
        int base = (b * 48 + n) * 192 + h * 8 + jj;
        *(float4*)&qs[swz4(n, jj)] = Q4[base];
        *(float4*)&ks[swz4(n, jj)] = Q4[base + 64];   // K is +256 floats
    }
    __syncthreads();
    const float scale = 0.17677669529663687f;  // 1/sqrt(32)
    for (int e = tid; e < 2304; e += 256) {
        int qi = e / 48, ki = e % 48;
        float s = 0.f;
        #pragma unroll
        for (int jj = 0; jj < 8; ++jj) {
            float4 a = *(const float4*)&qs[swz4(qi, jj)];
            float4 c = *(const float4*)&ks[swz4(ki, jj)];
            s += a.x * c.x + a.y * c.y + a.z * c.z + a.w * c.w;
        }
        sc[qi * 49 + ki] = s * scale;
    }
    __syncthreads();
    if (tid < 48) {
        float mx = -1e30f;
        for (int k = 0; k < 48; ++k) mx = fmaxf(mx, sc[tid * 49 + k]);
        rmax[tid] = mx;
    }
    __syncthreads();
    float* Eb = E + (b * 8 + h) * 2304;
    for (int e = tid; e < 2304; e += 256) {
        int qi = e / 48, ki = e % 48;
        Eb[qi * 48 + ki] = __expf(sc[qi * 49 + ki] - rmax[qi]);
    }
}

// ---------- Launch 3: per-(agg,b,8-target-group) aggregation -> P, cnt ----------
__global__ __launch_bounds__(384) void aggregate_kernel(
    const float* __restrict__ E0, const float* __restrict__ E1,
    const float* __restrict__ QKV0, const float* __restrict__ QKV1,
    const int* __restrict__ sync_adj, const int* __restrict__ async_adj,
    float* __restrict__ P0, float* __restrict__ P1,
    float* __restrict__ cnt0, float* __restrict__ cnt1)
{
    __shared__ float Vs[48 * 256];      // 48 KB
    __shared__ float msk[8][48];
    __shared__ float invd[8][384];      // [tt][h*48+q]
    __shared__ float yv[8][384];        // [tt][h*48+k]
    int bid = blockIdx.x, tid = threadIdx.x;
    int agg = bid / 192, rem = bid % 192;
    int b = rem / 6, tg = rem % 6;
    const float* E = (agg ? E1 : E0) + b * 18432;
    const float* V = (agg ? QKV1 : QKV0) + b * 48 * 768 + 512;
    const int* adj = agg ? async_adj : sync_adj;
    float* P   = agg ? P1 : P0;
    float* cnt = agg ? cnt1 : cnt0;

    const float4* V4g = (const float4*)V;
    float4* Vs4w = (float4*)Vs;
    for (int e4 = tid; e4 < 3072; e4 += 384) {
        int k = e4 >> 6, d4 = e4 & 63;
        Vs4w[k * 64 + d4] = V4g[k * 192 + d4];
    }
    {
        int tt = tid / 48, s = tid % 48;
        msk[tt][s] = (adj[(b * 48 + s) * 48 + tg * 8 + tt] > 0) ? 1.f : 0.f;
    }
    __syncthreads();
    if (tid < 8) {
        float c = 0.f;
        for (int s = 0; s < 48; ++s) c += msk[tid][s];
        cnt[b * 48 + tg * 8 + tid] = c;
    }
    // Phase A: invd[tt][h,q] = m[q]/ (sum_k m[k] E[h,q,k])
    {
        int h = tid / 48, q = tid % 48;
        float4 ev[12];
        const float4* Er4 = (const float4*)(E + (h * 48 + q) * 48);
        #pragma unroll
        for (int kk = 0; kk < 12; ++kk) ev[kk] = Er4[kk];
        #pragma unroll
        for (int tt = 0; tt < 8; ++tt) {
            const float* mr = msk[tt];
            float s = 0.f;
            #pragma unroll
            for (int kk = 0; kk < 12; ++kk) {
                float4 m4 = *(const float4*)&mr[kk * 4];
                s += ev[kk].x * m4.x + ev[kk].y * m4.y + ev[kk].z * m4.z + ev[kk].w * m4.w;
            }
            invd[tt][tid] = (mr[q] > 0.f) ? (1.f / s) : 0.f;
        }
    }
    __syncthreads();
    // Phase B: yv[tt][h,k] = m[k] * sum_q E[h,q,k] * invd[tt][h,q]
    {
        int h = tid / 48, k = tid % 48;
        float accb[8];
        #pragma unroll
        for (int tt = 0; tt < 8; ++tt) accb[tt] = 0.f;
        const float* Eh = E + h * 2304 + k;
        for (int q4 = 0; q4 < 12; ++q4) {
            float e0 = Eh[(q4 * 4 + 0) * 48];
            float e1 = Eh[(q4 * 4 + 1) * 48];
            float e2 = Eh[(q4 * 4 + 2) * 48];
            float e3 = Eh[(q4 * 4 + 3) * 48];
            #pragma unroll
            for (int tt = 0; tt < 8; ++tt) {
                float4 iv = *(const float4*)&invd[tt][h * 48 + q4 * 4];
                accb[tt] += e0 * iv.x + e1 * iv.y + e2 * iv.z + e3 * iv.w;
            }
        }
        #pragma unroll
        for (int tt = 0; tt < 8; ++tt) yv[tt][tid] = msk[tt][k] * accb[tt];
    }
    __syncthreads();
    // Phase C: P[tt][d] = sum_k yv[tt][h(d)][k] * Vs[k][d]
    {
        const float4* Vs4 = (const float4*)Vs;
        float4* P4o = (float4*)(P + (b * 48 + tg * 8) * 256);
        for (int e4 = tid; e4 < 512; e4 += 384) {
            int tt = e4 >> 6, d4 = e4 & 63;
            const float* yr = &yv[tt][(d4 >> 3) * 48];
            float4 p = {0.f, 0.f, 0.f, 0.f};
            for (int k = 0; k < 48; ++k) {
                float yval = yr[k];
                float4 vv = Vs4[k * 64 + d4];
                p.x += yval * vv.x; p.y += yval * vv.y;
                p.z += yval * vv.z; p.w += yval * vv.w;
            }
            P4o[tt * 64 + d4] = p;
        }
    }
}

// ---------- Launch 4: final map (P @ Wc^T) + fallback + passthrough copy ----------
__global__ __launch_bounds__(256) void final_kernel(
    const float* __restrict__ P0, const float* __restrict__ P1,
    const float* __restrict__ cnt0, const float* __restrict__ cnt1,
    const float* __restrict__ Wc0, const float* __restrict__ Wc1,
    const float* __restrict__ bc0, const float* __restrict__ bc1,
    const float* __restrict__ abm, const float* __restrict__ sbm,
    const float* __restrict__ async_fea, const float* __restrict__ sync_fea,
    float* __restrict__ out)
{
    __shared__ float xs[1024], wt[2048];
    int bid = blockIdx.x, tid = threadIdx.x;
    int agg = bid / 192, rem = bid % 192;
    int rt = rem >> 2, ot = rem & 3;
    int rbase = rt * 32, ob = ot * 64;
    const float* P   = agg ? P1 : P0;
    const float* cnt = agg ? cnt1 : cnt0;
    const float* Wc  = agg ? Wc1 : Wc0;
    const float* bc  = agg ? bc1 : bc0;
    const float* bm  = agg ? sbm : abm;
    const float* fb  = agg ? sync_fea : async_fea;

    const float4* fb4 = (const float4*)fb;
    float4* out4 = (float4*)out;
    #pragma unroll
    for (int l = 0; l < 2; ++l) {
        int e4 = l * 256 + tid;
        int rr = e4 >> 4, cc = e4 & 15;
        out4[(rbase + rr) * 256 + 128 + agg * 64 + ot * 16 + cc] =
            fb4[(rbase + rr) * 64 + ot * 16 + cc];
    }

    int ty = tid >> 4, tx = tid & 15;
    float acc[2][4];
    #pragma unroll
    for (int i = 0; i < 2; ++i)
        #pragma unroll
        for (int j = 0; j < 4; ++j) acc[i][j] = 0.f;
    const float4* P4 = (const float4*)P;
    const float4* W4 = (const float4*)Wc;
    for (int ch = 0; ch < 8; ++ch) {
        __syncthreads();
        {
            int rr = tid >> 3, jj = tid & 7;
            *(float4*)&xs[swz4(rr, jj)] = P4[(rbase + rr) * 64 + ch * 8 + jj];
        }
        #pragma unroll
        for (int l = 0; l < 2; ++l) {
            int e4 = l * 256 + tid;
            int rr = e4 >> 3, jj = e4 & 7;
            *(float4*)&wt[swz4(rr, jj)] = W4[(ob + rr) * 64 + ch * 8 + jj];
        }
        __syncthreads();
        #pragma unroll
        for (int jj = 0; jj < 8; ++jj) {
            float4 xv[2], wv[4];
            #pragma unroll
            for (int i = 0; i < 2; ++i) xv[i] = *(const float4*)&xs[swz4(ty * 2 + i, jj)];
            #pragma unroll
            for (int j = 0; j < 4; ++j) wv[j] = *(const float4*)&wt[swz4(j * 16 + tx, jj)];
            #pragma unroll
            for (int i = 0; i < 2; ++i)
                #pragma unroll
                for (int j = 0; j < 4; ++j)
                    acc[i][j] += xv[i].x * wv[j].x + xv[i].y * wv[j].y
                               + xv[i].z * wv[j].z + xv[i].w * wv[j].w;
        }
    }
    #pragma unroll
    for (int i = 0; i < 2; ++i) {
        int row = rbase + ty * 2 + i;
        float c = cnt[row];
        bool has = c > 0.f;
        float inv1 = has ? 1.f / c : 0.f;
        float inv2 = inv1 * inv1;
        #pragma unroll
        for (int j = 0; j < 4; ++j) {
            int o = ob + j * 16 + tx;
            float val = has ? acc[i][j] * inv2 + bc[o] * inv1 + bm[o]
                            : fb[row * 256 + o];
            out[row * 1024 + agg * 256 + o] = val;
        }
    }
}

extern "C" void kernel_launch(void* const* d_in, const int* in_sizes, int n_in,
                              void* d_out, int out_size, void* d_ws, size_t ws_size,
                              hipStream_t stream)
{
    const float* async_fea = (const float*)d_in[0];
    const float* sync_fea  = (const float*)d_in[1];
    const int*   async_adj = (const int*)d_in[2];
    const int*   sync_adj  = (const int*)d_in[3];
    const float* aWq = (const float*)d_in[4];
    const float* abq = (const float*)d_in[5];
    const float* aWk = (const float*)d_in[6];
    const float* abk = (const float*)d_in[7];
    const float* aWv = (const float*)d_in[8];
    const float* abv = (const float*)d_in[9];
    const float* aWo = (const float*)d_in[10];
    const float* abo = (const float*)d_in[11];
    const float* aWm = (const float*)d_in[12];
    const float* abm = (const float*)d_in[13];
    const float* sWq = (const float*)d_in[14];
    const float* sbq = (const float*)d_in[15];
    const float* sWk = (const float*)d_in[16];
    const float* sbk = (const float*)d_in[17];
    const float* sWv = (const float*)d_in[18];
    const float* sbv = (const float*)d_in[19];
    const float* sWo = (const float*)d_in[20];
    const float* sbo = (const float*)d_in[21];
    const float* sWm = (const float*)d_in[22];
    const float* sbm = (const float*)d_in[23];

    float* ws_f = (float*)d_ws;
    float* QKV0 = ws_f;                    // 1536*768
    float* QKV1 = QKV0 + 1179648;
    float* E0   = QKV1 + 1179648;          // 32*8*48*48
    float* E1   = E0 + 589824;
    float* P0   = E1 + 589824;             // 1536*256
    float* P1   = P0 + 393216;
    float* cnt0 = P1 + 393216;             // 1536
    float* cnt1 = cnt0 + 1536;
    float* Wc0  = cnt1 + 1536;             // 256*256
    float* Wc1  = Wc0 + 65536;
    float* bc0  = Wc1 + 65536;             // 256
    float* bc1  = bc0 + 256;
    unsigned short* Xb = (unsigned short*)(bc1 + 256);    // 786432 ushort
    unsigned short* Wb = Xb + 786432;                     // 393216 ushort

    convert_fold_kernel<<<640, 256, 0, stream>>>(
        async_fea, sync_fea,
        aWq, aWk, aWv, sWq, sWk, sWv,
        aWm, aWo, abo, sWm, sWo, sbo,
        Xb, Wb, Wc0, Wc1, bc0, bc1);
    qkv_mfma<<<576, 256, 0, stream>>>(Xb, Wb, abq, abk, abv, sbq, sbk, sbv, QKV0, QKV1);
    scores_kernel<<<512, 256, 0, stream>>>(QKV0, QKV1, E0, E1);
    aggregate_kernel<<<384, 384, 0, stream>>>(E0, E1, QKV0, QKV1,
                                              sync_adj, async_adj, P0, P1, cnt0, cnt1);
    final_kernel<<<384, 256, 0, stream>>>(P0, P1, cnt0, cnt1, Wc0, Wc1, bc0, bc1,
                                          abm, sbm, async_fea, sync_fea, (float*)d_out);
}

// Round 4
// 74.397 us; speedup vs baseline: 2.6220x; 1.2356x over previous
//
#include <hip/hip_runtime.h>

#define DD 256
#define HH 8
#define NN 48
#define BB 32

typedef __attribute__((ext_vector_type(8))) short short8v;   // 8 bf16 (4 VGPRs)
typedef __attribute__((ext_vector_type(4))) float f32x4;

// Swizzled float-index for LDS tiles with 32-float (128 B) rows.
__device__ __forceinline__ int swz4(int row, int jj) {
    return (row << 5) + ((jj ^ (row & 7)) << 2);
}

// fp32 -> bf16 RNE (scalar)
__device__ __forceinline__ unsigned short f2bf(float f) {
    union { float f; unsigned u; } v; v.f = f;
    unsigned u = v.u;
    return (unsigned short)((u + 0x7FFFu + ((u >> 16) & 1u)) >> 16);
}

// 8 consecutive fp32 -> bf16x8 fragment via v_cvt_pk_bf16_f32
__device__ __forceinline__ short8v cvt8(const float* p) {
    float4 lo = *(const float4*)p;
    float4 hi = *(const float4*)(p + 4);
    union { uint4 u; short8v s; } r;
    asm("v_cvt_pk_bf16_f32 %0, %1, %2" : "=v"(r.u.x) : "v"(lo.x), "v"(lo.y));
    asm("v_cvt_pk_bf16_f32 %0, %1, %2" : "=v"(r.u.y) : "v"(lo.z), "v"(lo.w));
    asm("v_cvt_pk_bf16_f32 %0, %1, %2" : "=v"(r.u.z) : "v"(hi.x), "v"(hi.y));
    asm("v_cvt_pk_bf16_f32 %0, %1, %2" : "=v"(r.u.w) : "v"(hi.z), "v"(hi.w));
    return r.s;
}

// 8 bf16 from LDS (2x float4 slots) -> frag
__device__ __forceinline__ short8v cvt8_lds(const float* p) {
    float4 lo = *(const float4*)p;
    float4 hi = *(const float4*)(p + 4);
    union { uint4 u; short8v s; } r;
    asm("v_cvt_pk_bf16_f32 %0, %1, %2" : "=v"(r.u.x) : "v"(lo.x), "v"(lo.y));
    asm("v_cvt_pk_bf16_f32 %0, %1, %2" : "=v"(r.u.y) : "v"(lo.z), "v"(lo.w));
    asm("v_cvt_pk_bf16_f32 %0, %1, %2" : "=v"(r.u.z) : "v"(hi.x), "v"(hi.y));
    asm("v_cvt_pk_bf16_f32 %0, %1, %2" : "=v"(r.u.w) : "v"(hi.z), "v"(hi.w));
    return r.s;
}

// ---------- Launch 1: QKV MFMA (blocks 0..575) + fold MFMA (576..607) ----------
// qkv: block = 64 rows x 64 cols of QKV[agg] (1536x768), K=256. Direct global
//      frag loads (fp32) with in-register bf16 convert.
// fold: block = 64x64 tile of Wc = Wm @ Wo, Wo transposed through LDS.
__global__ __launch_bounds__(256) void qkv_fold(
    const float* __restrict__ async_fea, const float* __restrict__ sync_fea,
    const float* __restrict__ aWq, const float* __restrict__ abq,
    const float* __restrict__ aWk, const float* __restrict__ abk,
    const float* __restrict__ aWv, const float* __restrict__ abv,
    const float* __restrict__ aWm, const float* __restrict__ aWo, const float* __restrict__ abo,
    const float* __restrict__ sWq, const float* __restrict__ sbq,
    const float* __restrict__ sWk, const float* __restrict__ sbk,
    const float* __restrict__ sWv, const float* __restrict__ sbv,
    const float* __restrict__ sWm, const float* __restrict__ sWo, const float* __restrict__ sbo,
    float* __restrict__ QKV0, float* __restrict__ QKV1,
    unsigned short* __restrict__ Wcb0, unsigned short* __restrict__ Wcb1,
    float* __restrict__ bc0, float* __restrict__ bc1)
{
    __shared__ float smem[2304];         // fold: WoT[64][36]
    int bid = blockIdx.x, tid = threadIdx.x;
    int wave = tid >> 6, lane = tid & 63;
    int l15 = lane & 15, l16 = (lane >> 4) << 3;

    if (bid < 576) {
        int agg = bid / 288, rem = bid % 288;
        int rt = rem / 12, ct = rem % 12;
        int row0 = rt * 64 + wave * 16;
        int col0 = ct * 64;
        int mat = ct >> 2;
        const float* X = agg ? async_fea : sync_fea;
        const float* W;
        const float* bias;
        if (agg == 0) {
            W    = (mat == 0) ? aWq : (mat == 1) ? aWk : aWv;
            bias = (mat == 0) ? abq : (mat == 1) ? abk : abv;
        } else {
            W    = (mat == 0) ? sWq : (mat == 1) ? sWk : sWv;
            bias = (mat == 0) ? sbq : (mat == 1) ? sbk : sbv;
        }
        const float* Xp = X + (row0 + l15) * 256 + l16;
        const float* Wp = W + ((ct & 3) * 64 + l15) * 256 + l16;
        f32x4 acc[4] = {{0,0,0,0},{0,0,0,0},{0,0,0,0},{0,0,0,0}};
        #pragma unroll
        for (int kk = 0; kk < 256; kk += 32) {
            short8v a = cvt8(Xp + kk);
            #pragma unroll
            for (int j = 0; j < 4; ++j) {
                short8v b = cvt8(Wp + j * 16 * 256 + kk);
                acc[j] = __builtin_amdgcn_mfma_f32_16x16x32_bf16(a, b, acc[j], 0, 0, 0);
            }
        }
        float* outQ = agg ? QKV1 : QKV0;
        #pragma unroll
        for (int j = 0; j < 4; ++j) {
            float bv = bias[(ct & 3) * 64 + j * 16 + l15];
            #pragma unroll
            for (int i = 0; i < 4; ++i) {
                int m = ((lane >> 4) << 2) + i;
                outQ[(row0 + m) * 768 + col0 + j * 16 + l15] = acc[j][i] + bv;
            }
        }
    } else {
        int fid = bid - 576;                 // 0..31
        int agg = fid >> 4, tile = fid & 15;
        int cb = (tile >> 2) * 64, db = (tile & 3) * 64;
        const float* Wm = agg ? sWm : aWm;
        const float* Wo = agg ? sWo : aWo;
        const float* bo = agg ? sbo : abo;
        unsigned short* Wcb = agg ? Wcb1 : Wcb0;
        float* bc = agg ? bc1 : bc0;
        int crow = cb + wave * 16 + l15;
        const float* Wmp = Wm + crow * 256 + l16;
        f32x4 acc[4] = {{0,0,0,0},{0,0,0,0},{0,0,0,0},{0,0,0,0}};
        for (int ch = 0; ch < 8; ++ch) {
            __syncthreads();
            // stage Wo[ch*32 .. +32][db .. +64] transposed -> WoT[d][i] with pad 36
            #pragma unroll
            for (int l = 0; l < 8; ++l) {
                int e = l * 256 + tid;
                int ii = e >> 6, dd = e & 63;
                smem[dd * 36 + ii] = Wo[(ch * 32 + ii) * 256 + db + dd];
            }
            __syncthreads();
            short8v a = cvt8(Wmp + ch * 32);
            #pragma unroll
            for (int j = 0; j < 4; ++j) {
                short8v b = cvt8_lds(&smem[(j * 16 + l15) * 36 + l16]);
                acc[j] = __builtin_amdgcn_mfma_f32_16x16x32_bf16(a, b, acc[j], 0, 0, 0);
            }
        }
        #pragma unroll
        for (int j = 0; j < 4; ++j)
            #pragma unroll
            for (int i = 0; i < 4; ++i) {
                int c = cb + wave * 16 + ((lane >> 4) << 2) + i;
                int d = db + j * 16 + l15;
                Wcb[c * 256 + d] = f2bf(acc[j][i]);
            }
        if ((tile & 3) == 0) {
            // bc[cb .. +64] = Wm rows . bo
            int r = tid >> 2, s = tid & 3;
            const float* wmr = Wm + (cb + r) * 256 + s * 64;
            const float* bor = bo + s * 64;
            float a = 0.f;
            #pragma unroll
            for (int i = 0; i < 64; ++i) a += wmr[i] * bor[i];
            a += __shfl_xor(a, 1);
            a += __shfl_xor(a, 2);
            if (s == 0) bc[cb + r] = a;
        }
    }
}

// ---------- Launch 2: E = exp(scores - rowmax), per (agg, b, h) ----------
__global__ __launch_bounds__(256) void scores_kernel(
    const float* __restrict__ QKV0, const float* __restrict__ QKV1,
    float* __restrict__ E0, float* __restrict__ E1)
{
    __shared__ float qs[1536], ks[1536], sc[48 * 49], rmax[48];
    int sid = blockIdx.x, tid = threadIdx.x;
    int agg = sid >> 8, bh = sid & 255;
    int b = bh >> 3, h = bh & 7;
    const float4* Q4 = (const float4*)(agg ? QKV1 : QKV0);
    float* E = agg ? E1 : E0;
    for (int e4 = tid; e4 < 384; e4 += 256) {
        int n = e4 >> 3, jj = e4 & 7;
        int base = (b * 48 + n) * 192 + h * 8 + jj;
        *(float4*)&qs[swz4(n, jj)] = Q4[base];
        *(float4*)&ks[swz4(n, jj)] = Q4[base + 64];   // K is +256 floats
    }
    __syncthreads();
    const float scale = 0.17677669529663687f;  // 1/sqrt(32)
    for (int e = tid; e < 2304; e += 256) {
        int qi = e / 48, ki = e % 48;
        float s = 0.f;
        #pragma unroll
        for (int jj = 0; jj < 8; ++jj) {
            float4 a = *(const float4*)&qs[swz4(qi, jj)];
            float4 c = *(const float4*)&ks[swz4(ki, jj)];
            s += a.x * c.x + a.y * c.y + a.z * c.z + a.w * c.w;
        }
        sc[qi * 49 + ki] = s * scale;
    }
    __syncthreads();
    if (tid < 48) {
        float mx = -1e30f;
        for (int k = 0; k < 48; ++k) mx = fmaxf(mx, sc[tid * 49 + k]);
        rmax[tid] = mx;
    }
    __syncthreads();
    float* Eb = E + (b * 8 + h) * 2304;
    for (int e = tid; e < 2304; e += 256) {
        int qi = e / 48, ki = e % 48;
        Eb[qi * 48 + ki] = __expf(sc[qi * 49 + ki] - rmax[qi]);
    }
}

// ---------- Launch 3: per-(agg,b,8-target-group) aggregation -> P(bf16), cnt ----------
__global__ __launch_bounds__(384) void aggregate_kernel(
    const float* __restrict__ E0, const float* __restrict__ E1,
    const float* __restrict__ QKV0, const float* __restrict__ QKV1,
    const int* __restrict__ sync_adj, const int* __restrict__ async_adj,
    unsigned short* __restrict__ Pb0, unsigned short* __restrict__ Pb1,
    float* __restrict__ cnt0, float* __restrict__ cnt1)
{
    __shared__ float Vs[48 * 256];      // 48 KB
    __shared__ float msk[8][48];
    __shared__ float invd[8][384];      // [tt][h*48+q]
    __shared__ float yv[8][384];        // [tt][h*48+k]
    int bid = blockIdx.x, tid = threadIdx.x;
    int agg = bid / 192, rem = bid % 192;
    int b = rem / 6, tg = rem % 6;
    const float* E = (agg ? E1 : E0) + b * 18432;
    const float* V = (agg ? QKV1 : QKV0) + b * 48 * 768 + 512;
    const int* adj = agg ? async_adj : sync_adj;
    unsigned short* Pb = agg ? Pb1 : Pb0;
    float* cnt = agg ? cnt1 : cnt0;

    const float4* V4g = (const float4*)V;
    float4* Vs4w = (float4*)Vs;
    for (int e4 = tid; e4 < 3072; e4 += 384) {
        int k = e4 >> 6, d4 = e4 & 63;
        Vs4w[k * 64 + d4] = V4g[k * 192 + d4];
    }
    {
        int tt = tid / 48, s = tid % 48;
        msk[tt][s] = (adj[(b * 48 + s) * 48 + tg * 8 + tt] > 0) ? 1.f : 0.f;
    }
    __syncthreads();
    if (tid < 8) {
        float c = 0.f;
        for (int s = 0; s < 48; ++s) c += msk[tid][s];
        cnt[b * 48 + tg * 8 + tid] = c;
    }
    // Phase A: invd[tt][h,q] = m[q]/ (sum_k m[k] E[h,q,k])
    {
        int h = tid / 48, q = tid % 48;
        float4 ev[12];
        const float4* Er4 = (const float4*)(E + (h * 48 + q) * 48);
        #pragma unroll
        for (int kk = 0; kk < 12; ++kk) ev[kk] = Er4[kk];
        #pragma unroll
        for (int tt = 0; tt < 8; ++tt) {
            const float* mr = msk[tt];
            float s = 0.f;
            #pragma unroll
            for (int kk = 0; kk < 12; ++kk) {
                float4 m4 = *(const float4*)&mr[kk * 4];
                s += ev[kk].x * m4.x + ev[kk].y * m4.y + ev[kk].z * m4.z + ev[kk].w * m4.w;
            }
            invd[tt][tid] = (mr[q] > 0.f) ? (1.f / s) : 0.f;
        }
    }
    __syncthreads();
    // Phase B: yv[tt][h,k] = m[k] * sum_q E[h,q,k] * invd[tt][h,q]
    {
        int h = tid / 48, k = tid % 48;
        float accb[8];
        #pragma unroll
        for (int tt = 0; tt < 8; ++tt) accb[tt] = 0.f;
        const float* Eh = E + h * 2304 + k;
        for (int q4 = 0; q4 < 12; ++q4) {
            float e0 = Eh[(q4 * 4 + 0) * 48];
            float e1 = Eh[(q4 * 4 + 1) * 48];
            float e2 = Eh[(q4 * 4 + 2) * 48];
            float e3 = Eh[(q4 * 4 + 3) * 48];
            #pragma unroll
            for (int tt = 0; tt < 8; ++tt) {
                float4 iv = *(const float4*)&invd[tt][h * 48 + q4 * 4];
                accb[tt] += e0 * iv.x + e1 * iv.y + e2 * iv.z + e3 * iv.w;
            }
        }
        #pragma unroll
        for (int tt = 0; tt < 8; ++tt) yv[tt][tid] = msk[tt][k] * accb[tt];
    }
    __syncthreads();
    // Phase C: P[tt][d] = sum_k yv[tt][h(d)][k] * Vs[k][d]  -> bf16
    {
        const float4* Vs4 = (const float4*)Vs;
        for (int e4 = tid; e4 < 512; e4 += 384) {
            int tt = e4 >> 6, d4 = e4 & 63;
            const float* yr = &yv[tt][(d4 >> 3) * 48];
            float4 p = {0.f, 0.f, 0.f, 0.f};
            for (int k = 0; k < 48; ++k) {
                float yval = yr[k];
                float4 vv = Vs4[k * 64 + d4];
                p.x += yval * vv.x; p.y += yval * vv.y;
                p.z += yval * vv.z; p.w += yval * vv.w;
            }
            unsigned r0, r1;
            asm("v_cvt_pk_bf16_f32 %0, %1, %2" : "=v"(r0) : "v"(p.x), "v"(p.y));
            asm("v_cvt_pk_bf16_f32 %0, %1, %2" : "=v"(r1) : "v"(p.z), "v"(p.w));
            uint2 pk; pk.x = r0; pk.y = r1;
            *(uint2*)(Pb + (b * 48 + tg * 8 + tt) * 256 + d4 * 4) = pk;
        }
    }
}

// ---------- Launch 4: final MFMA (P_bf @ Wc_bf^T) + epilogue + passthrough ----------
__global__ __launch_bounds__(256) void final_mfma(
    const unsigned short* __restrict__ Pb0, const unsigned short* __restrict__ Pb1,
    const float* __restrict__ cnt0, const float* __restrict__ cnt1,
    const unsigned short* __restrict__ Wcb0, const unsigned short* __restrict__ Wcb1,
    const float* __restrict__ bc0, const float* __restrict__ bc1,
    const float* __restrict__ abm, const float* __restrict__ sbm,
    const float* __restrict__ async_fea, const float* __restrict__ sync_fea,
    float* __restrict__ out)
{
    int bid = blockIdx.x, tid = threadIdx.x;
    int wave = tid >> 6, lane = tid & 63;
    int l15 = lane & 15, l16 = (lane >> 4) << 3;
    int agg = bid / 96, rem = bid % 96;
    int rt = rem >> 2, ctile = rem & 3;
    int row0 = rt * 64 + wave * 16;      // t-rows (global over 1536)
    int col0 = ctile * 64;
    const unsigned short* Pb  = agg ? Pb1 : Pb0;
    const unsigned short* Wcb = agg ? Wcb1 : Wcb0;
    const float* cnt = agg ? cnt1 : cnt0;
    const float* bc  = agg ? bc1 : bc0;
    const float* bm  = agg ? sbm : abm;
    const float* fb  = agg ? sync_fea : async_fea;

    // passthrough copy: rows rt*64..+64, cols ctile*64..+64 -> out cols 512+agg*256+...
    const float4* fb4 = (const float4*)fb;
    float4* out4 = (float4*)out;
    #pragma unroll
    for (int l = 0; l < 4; ++l) {
        int e4 = l * 256 + tid;
        int rr = e4 >> 4, cc = e4 & 15;
        out4[(rt * 64 + rr) * 256 + 128 + agg * 64 + ctile * 16 + cc] =
            fb4[(rt * 64 + rr) * 64 + ctile * 16 + cc];
    }

    const unsigned short* Pp = Pb + (row0 + l15) * 256 + l16;
    const unsigned short* Wp = Wcb + (col0 + l15) * 256 + l16;
    f32x4 acc[4] = {{0,0,0,0},{0,0,0,0},{0,0,0,0},{0,0,0,0}};
    #pragma unroll
    for (int kk = 0; kk < 256; kk += 32) {
        short8v a = *(const short8v*)(Pp + kk);
        #pragma unroll
        for (int j = 0; j < 4; ++j) {
            short8v b = *(const short8v*)(Wp + j * 16 * 256 + kk);
            acc[j] = __builtin_amdgcn_mfma_f32_16x16x32_bf16(a, b, acc[j], 0, 0, 0);
        }
    }
    #pragma unroll
    for (int j = 0; j < 4; ++j) {
        int c = col0 + j * 16 + l15;
        float bcv = bc[c], bmv = bm[c];
        #pragma unroll
        for (int i = 0; i < 4; ++i) {
            int t = row0 + ((lane >> 4) << 2) + i;
            float cn = cnt[t];
            bool has = cn > 0.f;
            float inv1 = has ? 1.f / cn : 0.f;
            float inv2 = inv1 * inv1;
            float val = has ? acc[j][i] * inv2 + bcv * inv1 + bmv
                            : fb[t * 256 + c];
            out[t * 1024 + agg * 256 + c] = val;
        }
    }
}

extern "C" void kernel_launch(void* const* d_in, const int* in_sizes, int n_in,
                              void* d_out, int out_size, void* d_ws, size_t ws_size,
                              hipStream_t stream)
{
    const float* async_fea = (const float*)d_in[0];
    const float* sync_fea  = (const float*)d_in[1];
    const int*   async_adj = (const int*)d_in[2];
    const int*   sync_adj  = (const int*)d_in[3];
    const float* aWq = (const float*)d_in[4];
    const float* abq = (const float*)d_in[5];
    const float* aWk = (const float*)d_in[6];
    const float* abk = (const float*)d_in[7];
    const float* aWv = (const float*)d_in[8];
    const float* abv = (const float*)d_in[9];
    const float* aWo = (const float*)d_in[10];
    const float* abo = (const float*)d_in[11];
    const float* aWm = (const float*)d_in[12];
    const float* abm = (const float*)d_in[13];
    const float* sWq = (const float*)d_in[14];
    const float* sbq = (const float*)d_in[15];
    const float* sWk = (const float*)d_in[16];
    const float* sbk = (const float*)d_in[17];
    const float* sWv = (const float*)d_in[18];
    const float* sbv = (const float*)d_in[19];
    const float* sWo = (const float*)d_in[20];
    const float* sbo = (const float*)d_in[21];
    const float* sWm = (const float*)d_in[22];
    const float* sbm = (const float*)d_in[23];

    float* ws_f = (float*)d_ws;
    float* QKV0 = ws_f;                        // 1179648
    float* QKV1 = QKV0 + 1179648;              // 1179648
    float* E0   = QKV1 + 1179648;              // 589824
    float* E1   = E0 + 589824;                 // 589824
    float* cnt0 = E1 + 589824;                 // 1536
    float* cnt1 = cnt0 + 1536;                 // 1536
    float* bc0  = cnt1 + 1536;                 // 256
    float* bc1  = bc0 + 256;                   // 256
    unsigned short* Pb0  = (unsigned short*)(bc1 + 256);   // 393216 ushort
    unsigned short* Pb1  = Pb0 + 393216;
    unsigned short* Wcb0 = Pb1 + 393216;                   // 65536 ushort
    unsigned short* Wcb1 = Wcb0 + 65536;

    qkv_fold<<<608, 256, 0, stream>>>(
        async_fea, sync_fea,
        aWq, abq, aWk, abk, aWv, abv, aWm, aWo, abo,
        sWq, sbq, sWk, sbk, sWv, sbv, sWm, sWo, sbo,
        QKV0, QKV1, Wcb0, Wcb1, bc0, bc1);
    scores_kernel<<<512, 256, 0, stream>>>(QKV0, QKV1, E0, E1);
    aggregate_kernel<<<384, 384, 0, stream>>>(E0, E1, QKV0, QKV1,
                                              sync_adj, async_adj, Pb0, Pb1, cnt0, cnt1);
    final_mfma<<<192, 256, 0, stream>>>(Pb0, Pb1, cnt0, cnt1, Wcb0, Wcb1, bc0, bc1,
                                        abm, sbm, async_fea, sync_fea, (float*)d_out);
}

// Round 5
// 61.361 us; speedup vs baseline: 3.1790x; 1.2124x over previous
//
#include <hip/hip_runtime.h>

#define DD 256
#define HH 8
#define NN 48
#define BB 32

typedef __attribute__((ext_vector_type(8))) short short8v;   // 8 bf16 (4 VGPRs)
typedef __attribute__((ext_vector_type(4))) float f32x4;

// fp32 -> bf16 RNE (scalar)
__device__ __forceinline__ unsigned short f2bf(float f) {
    union { float f; unsigned u; } v; v.f = f;
    unsigned u = v.u;
    return (unsigned short)((u + 0x7FFFu + ((u >> 16) & 1u)) >> 16);
}

// 8 consecutive fp32 -> bf16x8 fragment via v_cvt_pk_bf16_f32
__device__ __forceinline__ short8v cvt8(const float* p) {
    float4 lo = *(const float4*)p;
    float4 hi = *(const float4*)(p + 4);
    union { uint4 u; short8v s; } r;
    asm("v_cvt_pk_bf16_f32 %0, %1, %2" : "=v"(r.u.x) : "v"(lo.x), "v"(lo.y));
    asm("v_cvt_pk_bf16_f32 %0, %1, %2" : "=v"(r.u.y) : "v"(lo.z), "v"(lo.w));
    asm("v_cvt_pk_bf16_f32 %0, %1, %2" : "=v"(r.u.z) : "v"(hi.x), "v"(hi.y));
    asm("v_cvt_pk_bf16_f32 %0, %1, %2" : "=v"(r.u.w) : "v"(hi.z), "v"(hi.w));
    return r.s;
}

// ---------- Launch 1: QKV MFMA (blocks 0..575) + fold MFMA (576..607) ----------
__global__ __launch_bounds__(256) void qkv_fold(
    const float* __restrict__ async_fea, const float* __restrict__ sync_fea,
    const float* __restrict__ aWq, const float* __restrict__ abq,
    const float* __restrict__ aWk, const float* __restrict__ abk,
    const float* __restrict__ aWv, const float* __restrict__ abv,
    const float* __restrict__ aWm, const float* __restrict__ aWo, const float* __restrict__ abo,
    const float* __restrict__ sWq, const float* __restrict__ sbq,
    const float* __restrict__ sWk, const float* __restrict__ sbk,
    const float* __restrict__ sWv, const float* __restrict__ sbv,
    const float* __restrict__ sWm, const float* __restrict__ sWo, const float* __restrict__ sbo,
    float* __restrict__ QKV0, float* __restrict__ QKV1,
    unsigned short* __restrict__ Wcb0, unsigned short* __restrict__ Wcb1,
    float* __restrict__ bc0, float* __restrict__ bc1)
{
    __shared__ float smem[2304];         // fold: WoT[64][36]
    int bid = blockIdx.x, tid = threadIdx.x;
    int wave = tid >> 6, lane = tid & 63;
    int l15 = lane & 15, l16 = (lane >> 4) << 3;

    if (bid < 576) {
        int agg = bid / 288, rem = bid % 288;
        int rt = rem / 12, ct = rem % 12;
        int row0 = rt * 64 + wave * 16;
        int col0 = ct * 64;
        int mat = ct >> 2;
        const float* X = agg ? async_fea : sync_fea;
        const float* W;
        const float* bias;
        if (agg == 0) {
            W    = (mat == 0) ? aWq : (mat == 1) ? aWk : aWv;
            bias = (mat == 0) ? abq : (mat == 1) ? abk : abv;
        } else {
            W    = (mat == 0) ? sWq : (mat == 1) ? sWk : sWv;
            bias = (mat == 0) ? sbq : (mat == 1) ? sbk : sbv;
        }
        const float* Xp = X + (row0 + l15) * 256 + l16;
        const float* Wp = W + ((ct & 3) * 64 + l15) * 256 + l16;
        f32x4 acc[4] = {{0,0,0,0},{0,0,0,0},{0,0,0,0},{0,0,0,0}};
        #pragma unroll
        for (int kk = 0; kk < 256; kk += 32) {
            short8v a = cvt8(Xp + kk);
            #pragma unroll
            for (int j = 0; j < 4; ++j) {
                short8v b = cvt8(Wp + j * 16 * 256 + kk);
                acc[j] = __builtin_amdgcn_mfma_f32_16x16x32_bf16(a, b, acc[j], 0, 0, 0);
            }
        }
        float* outQ = agg ? QKV1 : QKV0;
        #pragma unroll
        for (int j = 0; j < 4; ++j) {
            float bv = bias[(ct & 3) * 64 + j * 16 + l15];
            #pragma unroll
            for (int i = 0; i < 4; ++i) {
                int m = ((lane >> 4) << 2) + i;
                outQ[(row0 + m) * 768 + col0 + j * 16 + l15] = acc[j][i] + bv;
            }
        }
    } else {
        int fid = bid - 576;                 // 0..31
        int agg = fid >> 4, tile = fid & 15;
        int cb = (tile >> 2) * 64, db = (tile & 3) * 64;
        const float* Wm = agg ? sWm : aWm;
        const float* Wo = agg ? sWo : aWo;
        const float* bo = agg ? sbo : abo;
        unsigned short* Wcb = agg ? Wcb1 : Wcb0;
        float* bc = agg ? bc1 : bc0;
        int crow = cb + wave * 16 + l15;
        const float* Wmp = Wm + crow * 256 + l16;
        f32x4 acc[4] = {{0,0,0,0},{0,0,0,0},{0,0,0,0},{0,0,0,0}};
        for (int ch = 0; ch < 8; ++ch) {
            __syncthreads();
            #pragma unroll
            for (int l = 0; l < 8; ++l) {
                int e = l * 256 + tid;
                int ii = e >> 6, dd = e & 63;
                smem[dd * 36 + ii] = Wo[(ch * 32 + ii) * 256 + db + dd];
            }
            __syncthreads();
            short8v a = cvt8(Wmp + ch * 32);
            #pragma unroll
            for (int j = 0; j < 4; ++j) {
                float* sp = &smem[(j * 16 + l15) * 36 + l16];
                float4 lo = *(const float4*)sp;
                float4 hi = *(const float4*)(sp + 4);
                union { uint4 u; short8v s; } rb;
                asm("v_cvt_pk_bf16_f32 %0, %1, %2" : "=v"(rb.u.x) : "v"(lo.x), "v"(lo.y));
                asm("v_cvt_pk_bf16_f32 %0, %1, %2" : "=v"(rb.u.y) : "v"(lo.z), "v"(lo.w));
                asm("v_cvt_pk_bf16_f32 %0, %1, %2" : "=v"(rb.u.z) : "v"(hi.x), "v"(hi.y));
                asm("v_cvt_pk_bf16_f32 %0, %1, %2" : "=v"(rb.u.w) : "v"(hi.z), "v"(hi.w));
                acc[j] = __builtin_amdgcn_mfma_f32_16x16x32_bf16(a, rb.s, acc[j], 0, 0, 0);
            }
        }
        #pragma unroll
        for (int j = 0; j < 4; ++j)
            #pragma unroll
            for (int i = 0; i < 4; ++i) {
                int c = cb + wave * 16 + ((lane >> 4) << 2) + i;
                int d = db + j * 16 + l15;
                Wcb[c * 256 + d] = f2bf(acc[j][i]);
            }
        if ((tile & 3) == 0) {
            int r = tid >> 2, s = tid & 3;
            const float* wmr = Wm + (cb + r) * 256 + s * 64;
            const float* bor = bo + s * 64;
            float a = 0.f;
            #pragma unroll
            for (int i = 0; i < 64; ++i) a += wmr[i] * bor[i];
            a += __shfl_xor(a, 1);
            a += __shfl_xor(a, 2);
            if (s == 0) bc[cb + r] = a;
        }
    }
}

// ---------- Launch 2: mega — scores + softmax + aggregate + final GEMM + copy ----------
// grid: 256 = (agg 2) x (b 32) x (tg 4, 12 targets each); block 384 threads.
__global__ __launch_bounds__(384) void mega_kernel(
    const float* __restrict__ QKV0, const float* __restrict__ QKV1,
    const int* __restrict__ sync_adj, const int* __restrict__ async_adj,
    const unsigned short* __restrict__ Wcb0, const unsigned short* __restrict__ Wcb1,
    const float* __restrict__ bc0, const float* __restrict__ bc1,
    const float* __restrict__ abm, const float* __restrict__ sbm,
    const float* __restrict__ async_fea, const float* __restrict__ sync_fea,
    float* __restrict__ out)
{
    __shared__ float E_lds[8 * 48 * 49];       // stride 49: conflict-free rows AND cols
    __shared__ float msk[12 * 48];
    __shared__ float invd[12][384];            // [tt][h*48+q]
    __shared__ float yv[12][384];              // [tt][h*48+k]
    __shared__ unsigned short P_lds[16 * 264]; // bf16, pad 264
    __shared__ float cnt_l[12];

    int bid = blockIdx.x, tid = threadIdx.x;
    int agg = bid >> 7, rem = bid & 127;
    int b = rem >> 2, tg = rem & 3;
    int wave = tid >> 6, lane = tid & 63;
    int l15 = lane & 15, g = lane >> 4, l16 = g << 3;

    const float* QKV = agg ? QKV1 : QKV0;
    const int*   adj = agg ? async_adj : sync_adj;
    const float* fb  = agg ? sync_fea : async_fea;
    int row_base = b * 48 + tg * 12;

    // passthrough copy: this block's 12 rows, 256 out-cols (512 + agg*256 ..)
    {
        const float4* fb4 = (const float4*)fb;
        float4* out4 = (float4*)out;
        #pragma unroll
        for (int l = 0; l < 2; ++l) {
            int e = l * 384 + tid;
            int r = e >> 6, c = e & 63;
            out4[(row_base + r) * 256 + 128 + agg * 64 + c] =
                fb4[(row_base + r) * 64 + c];
        }
    }

    // neighbor masks for the 12 targets: m[tt][s] = adj[b][s][tg*12+tt] > 0
    for (int e = tid; e < 576; e += 384) {
        int tt = e / 48, s = e % 48;
        msk[tt * 48 + s] = (adj[(b * 48 + s) * 48 + tg * 12 + tt] > 0) ? 1.f : 0.f;
    }

    // ---- scores via MFMA: jobs (h, qt), 4 per wave ----
    const float scale = 0.17677669529663687f;  // 1/sqrt(32)
    #pragma unroll
    for (int jj = 0; jj < 4; ++jj) {
        int job = wave * 4 + jj;
        int h = job / 3, qt = job % 3;
        short8v a = cvt8(QKV + (b * 48 + qt * 16 + l15) * 768 + h * 32 + l16);
        f32x4 acc[3];
        #pragma unroll
        for (int kt = 0; kt < 3; ++kt) {
            short8v kb = cvt8(QKV + (b * 48 + kt * 16 + l15) * 768 + 256 + h * 32 + l16);
            f32x4 z = {0.f, 0.f, 0.f, 0.f};
            acc[kt] = __builtin_amdgcn_mfma_f32_16x16x32_bf16(a, kb, z, 0, 0, 0);
        }
        float sc[3][4], rm[4];
        #pragma unroll
        for (int i = 0; i < 4; ++i) {
            #pragma unroll
            for (int kt = 0; kt < 3; ++kt) sc[kt][i] = acc[kt][i] * scale;
            rm[i] = fmaxf(fmaxf(sc[0][i], sc[1][i]), sc[2][i]);
        }
        #pragma unroll
        for (int m = 1; m <= 8; m <<= 1) {
            #pragma unroll
            for (int i = 0; i < 4; ++i) rm[i] = fmaxf(rm[i], __shfl_xor(rm[i], m));
        }
        #pragma unroll
        for (int kt = 0; kt < 3; ++kt)
            #pragma unroll
            for (int i = 0; i < 4; ++i)
                E_lds[(h * 48 + qt * 16 + g * 4 + i) * 49 + kt * 16 + l15] =
                    __expf(sc[kt][i] - rm[i]);
    }
    __syncthreads();

    if (tid < 12) {
        float c = 0.f;
        for (int s = 0; s < 48; ++s) c += msk[tid * 48 + s];
        cnt_l[tid] = c;
    }

    // ---- Phase A: invd[tt][h,q] = m[q] / (sum_k m[k]*E[h,q,k]) ----
    {
        float erow[48];
        #pragma unroll
        for (int kk = 0; kk < 48; ++kk) erow[kk] = E_lds[tid * 49 + kk];
        int q = tid % 48;
        #pragma unroll
        for (int tt = 0; tt < 12; ++tt) {
            const float4* m4p = (const float4*)&msk[tt * 48];
            float s = 0.f;
            #pragma unroll
            for (int k4 = 0; k4 < 12; ++k4) {
                float4 m4 = m4p[k4];
                s += m4.x * erow[4 * k4] + m4.y * erow[4 * k4 + 1]
                   + m4.z * erow[4 * k4 + 2] + m4.w * erow[4 * k4 + 3];
            }
            float mq = msk[tt * 48 + q];
            invd[tt][tid] = (mq > 0.f) ? (1.f / s) : 0.f;
        }
    }
    __syncthreads();

    // ---- Phase B: yv[tt][h,k] = m[k] * sum_q E[h,q,k] * invd[tt][h,q] ----
    {
        int h = tid / 48, k = tid % 48;
        float ecol[48];
        #pragma unroll
        for (int q = 0; q < 48; ++q) ecol[q] = E_lds[(h * 48 + q) * 49 + k];
        #pragma unroll
        for (int tt = 0; tt < 12; ++tt) {
            const float4* iv4 = (const float4*)&invd[tt][h * 48];
            float s = 0.f;
            #pragma unroll
            for (int q4 = 0; q4 < 12; ++q4) {
                float4 v = iv4[q4];
                s += v.x * ecol[4 * q4] + v.y * ecol[4 * q4 + 1]
                   + v.z * ecol[4 * q4 + 2] + v.w * ecol[4 * q4 + 3];
            }
            yv[tt][tid] = msk[tt * 48 + k] * s;
        }
    }
    __syncthreads();

    // ---- Phase C: P[tt][d] = sum_k yv[tt][h(d)][k] * V[k][d]  -> bf16 LDS ----
    {
        for (int e = tid; e < 768; e += 384) {
            int tt = e >> 6, d4 = e & 63;
            int h = d4 >> 3;
            const float* yr = &yv[tt][h * 48];
            const float* Vp = QKV + b * 48 * 768 + 512 + d4 * 4;
            float4 p = {0.f, 0.f, 0.f, 0.f};
            for (int k = 0; k < 48; ++k) {
                float yval = yr[k];
                float4 vv = *(const float4*)(Vp + k * 768);
                p.x += yval * vv.x; p.y += yval * vv.y;
                p.z += yval * vv.z; p.w += yval * vv.w;
            }
            unsigned r0, r1;
            asm("v_cvt_pk_bf16_f32 %0, %1, %2" : "=v"(r0) : "v"(p.x), "v"(p.y));
            asm("v_cvt_pk_bf16_f32 %0, %1, %2" : "=v"(r1) : "v"(p.z), "v"(p.w));
            uint2 pk; pk.x = r0; pk.y = r1;
            *(uint2*)&P_lds[tt * 264 + d4 * 4] = pk;
        }
    }
    __syncthreads();

    // ---- final GEMM: P(16x256,bf16) @ Wc^T + epilogue ----
    const unsigned short* Wcb = agg ? Wcb1 : Wcb0;
    const float* bc = agg ? bc1 : bc0;
    const float* bm = agg ? sbm : abm;
    for (int ct = wave; ct < 16; ct += 6) {
        f32x4 acc = {0.f, 0.f, 0.f, 0.f};
        const unsigned short* Wp = Wcb + (ct * 16 + l15) * 256 + l16;
        const unsigned short* Pp = &P_lds[l15 * 264 + l16];
        #pragma unroll
        for (int kk = 0; kk < 8; ++kk) {
            short8v a = *(const short8v*)(Pp + kk * 32);
            short8v bfr = *(const short8v*)(Wp + kk * 32);
            acc = __builtin_amdgcn_mfma_f32_16x16x32_bf16(a, bfr, acc, 0, 0, 0);
        }
        int c = ct * 16 + l15;
        float bcv = bc[c], bmv = bm[c];
        #pragma unroll
        for (int i = 0; i < 4; ++i) {
            int t = g * 4 + i;
            if (t < 12) {
                int grow = row_base + t;
                float cn = cnt_l[t];
                float val;
                if (cn > 0.f) {
                    float inv1 = 1.f / cn;
                    val = acc[i] * inv1 * inv1 + bcv * inv1 + bmv;
                } else {
                    val = fb[grow * 256 + c];
                }
                out[grow * 1024 + agg * 256 + c] = val;
            }
        }
    }
}

extern "C" void kernel_launch(void* const* d_in, const int* in_sizes, int n_in,
                              void* d_out, int out_size, void* d_ws, size_t ws_size,
                              hipStream_t stream)
{
    const float* async_fea = (const float*)d_in[0];
    const float* sync_fea  = (const float*)d_in[1];
    const int*   async_adj = (const int*)d_in[2];
    const int*   sync_adj  = (const int*)d_in[3];
    const float* aWq = (const float*)d_in[4];
    const float* abq = (const float*)d_in[5];
    const float* aWk = (const float*)d_in[6];
    const float* abk = (const float*)d_in[7];
    const float* aWv = (const float*)d_in[8];
    const float* abv = (const float*)d_in[9];
    const float* aWo = (const float*)d_in[10];
    const float* abo = (const float*)d_in[11];
    const float* aWm = (const float*)d_in[12];
    const float* abm = (const float*)d_in[13];
    const float* sWq = (const float*)d_in[14];
    const float* sbq = (const float*)d_in[15];
    const float* sWk = (const float*)d_in[16];
    const float* sbk = (const float*)d_in[17];
    const float* sWv = (const float*)d_in[18];
    const float* sbv = (const float*)d_in[19];
    const float* sWo = (const float*)d_in[20];
    const float* sbo = (const float*)d_in[21];
    const float* sWm = (const float*)d_in[22];
    const float* sbm = (const float*)d_in[23];

    float* ws_f = (float*)d_ws;
    float* QKV0 = ws_f;                        // 1179648
    float* QKV1 = QKV0 + 1179648;              // 1179648
    float* bc0  = QKV1 + 1179648;              // 256
    float* bc1  = bc0 + 256;                   // 256
    unsigned short* Wcb0 = (unsigned short*)(bc1 + 256);   // 65536 ushort
    unsigned short* Wcb1 = Wcb0 + 65536;

    qkv_fold<<<608, 256, 0, stream>>>(
        async_fea, sync_fea,
        aWq, abq, aWk, abk, aWv, abv, aWm, aWo, abo,
        sWq, sbq, sWk, sbk, sWv, sbv, sWm, sWo, sbo,
        QKV0, QKV1, Wcb0, Wcb1, bc0, bc1);
    mega_kernel<<<256, 384, 0, stream>>>(
        QKV0, QKV1, sync_adj, async_adj, Wcb0, Wcb1, bc0, bc1,
        abm, sbm, async_fea, sync_fea, (float*)d_out);
}